// Round 7
// baseline (200.168 us; speedup 1.0000x reference)
//
#include <hip/hip_runtime.h>

// DiffeomorphicTransform: scaling-and-squaring integration of a velocity field.
//   flow = velocity / 2^7
//   repeat 7x: flow = flow + trilinear_sample(flow, sample_grid + flow_perm)
// Volume: B=1, C=3, D=H=W=128, f32.
//
// R2: AoS float4 flow -> 8 dwordx4 gathers/voxel. 92->50us/step.
// R3: separable grid -> 3x128 LDS axis tables (gather-transaction bound).
// R4: 2x2x2 supervoxel layout (one 128B line per 2x2x2 block). 278->201us.
// R5: FAILED global-gather fusion of init+step1 (scalar gather count rules).
// R6: blocked-order init (coalesced writes). 201->196us.
// R7: init+step1 fused via LDS tile: 8^3 tile + halo 4 (16^3 x 3f32 = 48KB),
//     vel staged coalesced & pre-scaled by 2^-7 (exact); 24 corner reads are
//     ds_reads. Exact in-tile check per thread; rare out-of-tile corners fall
//     back to global reads (correctness independent of data).

#define DD 128
#define HH 128
#define WW 128
#define NVOX (DD * HH * WW)          // 2,097,152
#define NELEM (3 * NVOX)             // 6,291,456
#define SCALE 63.5f                  // 0.5*(dim-1), same for x/y/z
#define INV128 (1.0f / 128.0f)

// float4-index of voxel (x,y,z) in the 2x2x2-blocked volume.
__device__ __forceinline__ int blk_addr4(int xc, int yc, int zc) {
    return ((zc >> 1) << 15) + ((yc >> 1) << 9) + ((xc >> 1) << 3)
         + ((zc & 1) << 2) + ((yc & 1) << 1) + (xc & 1);
}

// ---------------- fused init + step 1 ----------------
// One block = 8x8x8 output tile. Stages 16x16x16 halo tile of vel*2^-7 in LDS.
// Also extracts the 3x128 axis tables (block 0) for steps 2..7.
__global__ __launch_bounds__(512) void fused_step1_kernel(
    const float* __restrict__ vel,     // [3][D][H][W] planar
    const float* __restrict__ grid,    // [D][H][W][3]
    float4* __restrict__ dst4,         // blocked AoS out (step-1 flow)
    float* __restrict__ tbl) {         // [384] axis tables out
    __shared__ float s_vel[16 * 16 * 16 * 3];   // 48 KB, [cell][3], pre-scaled

    int tid = threadIdx.x;

    // Axis tables for later steps (block 0 only; bit-identical extraction).
    if (blockIdx.x == 0 && tid < 128) {
        tbl[tid]       = grid[3 * tid + 0];                  // t_x[w]
        tbl[128 + tid] = grid[(tid * WW) * 3 + 1];           // t_y[h]
        tbl[256 + tid] = grid[(tid * HH * WW) * 3 + 2];      // t_z[d]
    }

    int btx = blockIdx.x & 15, bty = (blockIdx.x >> 4) & 15, btz = blockIdx.x >> 8;
    int tx = btx << 3, ty = bty << 3, tz = btz << 3;   // tile origin (output)
    int ox = tx - 4, oy = ty - 4, oz = tz - 4;         // staged-region origin

    // ---- stage 16^3 x 3ch, clamped, pre-scaled (exact *2^-7) ----
    #pragma unroll
    for (int c = 0; c < 3; ++c) {
        const float* p = vel + c * NVOX;
        #pragma unroll
        for (int k = 0; k < 8; ++k) {
            int cell = tid + (k << 9);                 // 0..4095
            int xx = cell & 15, yy = (cell >> 4) & 15, zz = cell >> 8;
            int gx = min(max(ox + xx, 0), WW - 1);
            int gy = min(max(oy + yy, 0), HH - 1);
            int gz = min(max(oz + zz, 0), DD - 1);
            s_vel[cell * 3 + c] = p[(gz * HH + gy) * WW + gx] * INV128;
        }
    }
    __syncthreads();

    // ---- compute: thread -> (voxel, blocked gid), write-coalesced order ----
    int phase = tid & 7;
    int svl = tid >> 3;                                // 0..63 local supervoxel
    int vx = tx + (((svl & 3) << 1) | (phase & 1));
    int vy = ty + ((((svl >> 2) & 3) << 1) | ((phase >> 1) & 1));
    int vz = tz + ((((svl >> 4) & 3) << 1) | ((phase >> 2) & 1));

    // Self flow from LDS (interior of tile, always valid).
    int ls = (((vz - oz) * 16) + (vy - oy)) * 16 + (vx - ox);
    float fx = s_vel[ls * 3 + 0];
    float fy = s_vel[ls * 3 + 1];
    float fz = s_vel[ls * 3 + 2];

    // Grid values for own voxel (bit-identical: read the input).
    int lin = (vz * HH + vy) * WW + vx;
    float gxv = grid[3 * lin + 0];
    float gyv = grid[3 * lin + 1];
    float gzv = grid[3 * lin + 2];

    float xs = (gxv + fx + 1.0f) * SCALE;
    float ys = (gyv + fy + 1.0f) * SCALE;
    float zs = (gzv + fz + 1.0f) * SCALE;

    float x0f = floorf(xs), y0f = floorf(ys), z0f = floorf(zs);
    float wx = xs - x0f, wy = ys - y0f, wz = zs - z0f;
    float omx = 1.0f - wx, omy = 1.0f - wy, omz = 1.0f - wz;

    int x0 = min(max((int)x0f, 0), WW - 1);
    int x1 = min(max((int)x0f + 1, 0), WW - 1);
    int y0 = min(max((int)y0f, 0), HH - 1);
    int y1 = min(max((int)y0f + 1, 0), HH - 1);
    int z0 = min(max((int)z0f, 0), DD - 1);
    int z1 = min(max((int)z0f + 1, 0), DD - 1);

    float vxo, vyo, vzo;
    bool in_tile = (x0 >= ox) && (x1 <= ox + 15) &&
                   (y0 >= oy) && (y1 <= oy + 15) &&
                   (z0 >= oz) && (z1 <= oz + 15);
    if (in_tile) {
        int i000 = ((z0 - oz) * 16 + (y0 - oy)) * 16 + (x0 - ox);
        int i001 = ((z0 - oz) * 16 + (y0 - oy)) * 16 + (x1 - ox);
        int i010 = ((z0 - oz) * 16 + (y1 - oy)) * 16 + (x0 - ox);
        int i011 = ((z0 - oz) * 16 + (y1 - oy)) * 16 + (x1 - ox);
        int i100 = ((z1 - oz) * 16 + (y0 - oy)) * 16 + (x0 - ox);
        int i101 = ((z1 - oz) * 16 + (y0 - oy)) * 16 + (x1 - ox);
        int i110 = ((z1 - oz) * 16 + (y1 - oy)) * 16 + (x0 - ox);
        int i111 = ((z1 - oz) * 16 + (y1 - oy)) * 16 + (x1 - ox);
        #pragma unroll
        for (int c = 0; c < 3; ++c) {
            float c000 = s_vel[i000 * 3 + c], c001 = s_vel[i001 * 3 + c];
            float c010 = s_vel[i010 * 3 + c], c011 = s_vel[i011 * 3 + c];
            float c100 = s_vel[i100 * 3 + c], c101 = s_vel[i101 * 3 + c];
            float c110 = s_vel[i110 * 3 + c], c111 = s_vel[i111 * 3 + c];
            float t = (c000 * omx + c001 * wx) * omy + (c010 * omx + c011 * wx) * wy;
            float b = (c100 * omx + c101 * wx) * omy + (c110 * omx + c111 * wx) * wy;
            float v = t * omz + b * wz;
            if (c == 0) vxo = v; else if (c == 1) vyo = v; else vzo = v;
        }
    } else {
        // Rare fallback: global planar gathers, identical math (vel*2^-7 exact).
        int o00 = (z0 * HH + y0) * WW;
        int o01 = (z0 * HH + y1) * WW;
        int o10 = (z1 * HH + y0) * WW;
        int o11 = (z1 * HH + y1) * WW;
        #pragma unroll
        for (int c = 0; c < 3; ++c) {
            const float* p = vel + c * NVOX;
            float c000 = p[o00 + x0] * INV128, c001 = p[o00 + x1] * INV128;
            float c010 = p[o01 + x0] * INV128, c011 = p[o01 + x1] * INV128;
            float c100 = p[o10 + x0] * INV128, c101 = p[o10 + x1] * INV128;
            float c110 = p[o11 + x0] * INV128, c111 = p[o11 + x1] * INV128;
            float t = (c000 * omx + c001 * wx) * omy + (c010 * omx + c011 * wx) * wy;
            float b = (c100 * omx + c101 * wx) * omy + (c110 * omx + c111 * wx) * wy;
            float v = t * omz + b * wz;
            if (c == 0) vxo = v; else if (c == 1) vyo = v; else vzo = v;
        }
    }

    float4 o;
    o.x = fx + vxo;
    o.y = fy + vyo;
    o.z = fz + vzo;
    o.w = 0.0f;
    dst4[blk_addr4(vx, vy, vz)] = o;   // coalesced (phase-fastest order)
}

// ---------------- warp step, blocked layout ----------------
template <bool PLANAR_OUT>
__global__ __launch_bounds__(256) void warp_step_blk_kernel(
    const float4* __restrict__ src,    // blocked AoS flow
    const float* __restrict__ tbl,     // [384] axis tables
    float4* __restrict__ dst4,         // blocked AoS out (if !PLANAR_OUT)
    float* __restrict__ dstp) {        // planar out (if PLANAR_OUT)
    __shared__ float s_tx[128], s_ty[128], s_tz[128];
    int tid = threadIdx.x;
    if (tid < 128) {
        s_tx[tid] = tbl[tid];
        s_tz[tid] = tbl[256 + tid];
    } else {
        s_ty[tid - 128] = tbl[tid];
    }
    __syncthreads();

    int gid = blockIdx.x * blockDim.x + threadIdx.x;
    if (gid >= NVOX) return;

    int phase = gid & 7;
    int sv = gid >> 3;
    int x = ((sv & 63) << 1) | (phase & 1);
    int y = (((sv >> 6) & 63) << 1) | ((phase >> 1) & 1);
    int z = ((sv >> 12) << 1) | ((phase >> 2) & 1);

    float4 f = src[gid];               // coalesced self-read

    float xs = (s_tx[x] + f.x + 1.0f) * SCALE;
    float ys = (s_ty[y] + f.y + 1.0f) * SCALE;
    float zs = (s_tz[z] + f.z + 1.0f) * SCALE;

    float x0f = floorf(xs), y0f = floorf(ys), z0f = floorf(zs);
    float wx = xs - x0f, wy = ys - y0f, wz = zs - z0f;
    float omx = 1.0f - wx, omy = 1.0f - wy, omz = 1.0f - wz;

    int x0 = min(max((int)x0f, 0), WW - 1);
    int x1 = min(max((int)x0f + 1, 0), WW - 1);
    int y0 = min(max((int)y0f, 0), HH - 1);
    int y1 = min(max((int)y0f + 1, 0), HH - 1);
    int z0 = min(max((int)z0f, 0), DD - 1);
    int z1 = min(max((int)z0f + 1, 0), DD - 1);

    float4 c000 = src[blk_addr4(x0, y0, z0)];
    float4 c001 = src[blk_addr4(x1, y0, z0)];
    float4 c010 = src[blk_addr4(x0, y1, z0)];
    float4 c011 = src[blk_addr4(x1, y1, z0)];
    float4 c100 = src[blk_addr4(x0, y0, z1)];
    float4 c101 = src[blk_addr4(x1, y0, z1)];
    float4 c110 = src[blk_addr4(x0, y1, z1)];
    float4 c111 = src[blk_addr4(x1, y1, z1)];

    float vx, vy, vzv;
    {
        float t, b;
        t = (c000.x * omx + c001.x * wx) * omy + (c010.x * omx + c011.x * wx) * wy;
        b = (c100.x * omx + c101.x * wx) * omy + (c110.x * omx + c111.x * wx) * wy;
        vx = t * omz + b * wz;
        t = (c000.y * omx + c001.y * wx) * omy + (c010.y * omx + c011.y * wx) * wy;
        b = (c100.y * omx + c101.y * wx) * omy + (c110.y * omx + c111.y * wx) * wy;
        vy = t * omz + b * wz;
        t = (c000.z * omx + c001.z * wx) * omy + (c010.z * omx + c011.z * wx) * wy;
        b = (c100.z * omx + c101.z * wx) * omy + (c110.z * omx + c111.z * wx) * wy;
        vzv = t * omz + b * wz;
    }

    if (PLANAR_OUT) {
        int lin = (z * HH + y) * WW + x;
        dstp[lin] = f.x + vx;
        dstp[NVOX + lin] = f.y + vy;
        dstp[2 * NVOX + lin] = f.z + vzv;
    } else {
        float4 o;
        o.x = f.x + vx;
        o.y = f.y + vy;
        o.z = f.z + vzv;
        o.w = 0.0f;
        dst4[gid] = o;                 // coalesced
    }
}

// ---------------- linear-AoS path (fallback, mid ws) ----------------
__global__ __launch_bounds__(256) void init_flow_aos_kernel(
    const float* __restrict__ vel, float4* __restrict__ flow) {
    int i = blockIdx.x * blockDim.x + threadIdx.x;
    if (i >= NVOX) return;
    float4 f;
    f.x = vel[i] * INV128;
    f.y = vel[NVOX + i] * INV128;
    f.z = vel[2 * NVOX + i] * INV128;
    f.w = 0.0f;
    flow[i] = f;
}

template <bool PLANAR_OUT>
__global__ __launch_bounds__(256) void warp_step_aos_kernel(
    const float4* __restrict__ src, const float* __restrict__ grid,
    float4* __restrict__ dst4, float* __restrict__ dstp) {
    int idx = blockIdx.x * blockDim.x + threadIdx.x;
    if (idx >= NVOX) return;

    float4 f = src[idx];
    float gx = grid[3 * idx + 0];
    float gy = grid[3 * idx + 1];
    float gz = grid[3 * idx + 2];

    float x = (gx + f.x + 1.0f) * SCALE;
    float y = (gy + f.y + 1.0f) * SCALE;
    float z = (gz + f.z + 1.0f) * SCALE;

    float x0f = floorf(x), y0f = floorf(y), z0f = floorf(z);
    float wx = x - x0f, wy = y - y0f, wz = z - z0f;
    float omx = 1.0f - wx, omy = 1.0f - wy, omz = 1.0f - wz;

    int x0 = min(max((int)x0f, 0), WW - 1);
    int x1 = min(max((int)x0f + 1, 0), WW - 1);
    int y0 = min(max((int)y0f, 0), HH - 1);
    int y1 = min(max((int)y0f + 1, 0), HH - 1);
    int z0 = min(max((int)z0f, 0), DD - 1);
    int z1 = min(max((int)z0f + 1, 0), DD - 1);

    const float4* r00 = src + (z0 * HH + y0) * WW;
    const float4* r01 = src + (z0 * HH + y1) * WW;
    const float4* r10 = src + (z1 * HH + y0) * WW;
    const float4* r11 = src + (z1 * HH + y1) * WW;

    float4 c000 = r00[x0], c001 = r00[x1];
    float4 c010 = r01[x0], c011 = r01[x1];
    float4 c100 = r10[x0], c101 = r10[x1];
    float4 c110 = r11[x0], c111 = r11[x1];

    float vx, vy, vzv;
    {
        float t, b;
        t = (c000.x * omx + c001.x * wx) * omy + (c010.x * omx + c011.x * wx) * wy;
        b = (c100.x * omx + c101.x * wx) * omy + (c110.x * omx + c111.x * wx) * wy;
        vx = t * omz + b * wz;
        t = (c000.y * omx + c001.y * wx) * omy + (c010.y * omx + c011.y * wx) * wy;
        b = (c100.y * omx + c101.y * wx) * omy + (c110.y * omx + c111.y * wx) * wy;
        vy = t * omz + b * wz;
        t = (c000.z * omx + c001.z * wx) * omy + (c010.z * omx + c011.z * wx) * wy;
        b = (c100.z * omx + c101.z * wx) * omy + (c110.z * omx + c111.z * wx) * wy;
        vzv = t * omz + b * wz;
    }

    if (PLANAR_OUT) {
        dstp[idx] = f.x + vx;
        dstp[NVOX + idx] = f.y + vy;
        dstp[2 * NVOX + idx] = f.z + vzv;
    } else {
        float4 o;
        o.x = f.x + vx; o.y = f.y + vy; o.z = f.z + vzv; o.w = 0.0f;
        dst4[idx] = o;
    }
}

// ---------------- planar fallback (tiny ws) ----------------
__global__ __launch_bounds__(256) void init_flow_kernel(
    const float* __restrict__ vel, float* __restrict__ flow) {
    int i = blockIdx.x * blockDim.x + threadIdx.x;
    if (i < NELEM) flow[i] = vel[i] * INV128;
}

__global__ __launch_bounds__(256) void warp_step_kernel(
    const float* __restrict__ src, const float* __restrict__ grid,
    float* __restrict__ dst) {
    int idx = blockIdx.x * blockDim.x + threadIdx.x;
    if (idx >= NVOX) return;

    float fx = src[idx];
    float fy = src[NVOX + idx];
    float fz = src[2 * NVOX + idx];
    float gx = grid[idx * 3 + 0];
    float gy = grid[idx * 3 + 1];
    float gz = grid[idx * 3 + 2];

    float x = (gx + fx + 1.0f) * SCALE;
    float y = (gy + fy + 1.0f) * SCALE;
    float z = (gz + fz + 1.0f) * SCALE;

    float x0f = floorf(x), y0f = floorf(y), z0f = floorf(z);
    float wx = x - x0f, wy = y - y0f, wz = z - z0f;

    int x0 = min(max((int)x0f, 0), WW - 1);
    int x1 = min(max((int)x0f + 1, 0), WW - 1);
    int y0 = min(max((int)y0f, 0), HH - 1);
    int y1 = min(max((int)y0f + 1, 0), HH - 1);
    int z0 = min(max((int)z0f, 0), DD - 1);
    int z1 = min(max((int)z0f + 1, 0), DD - 1);

    int o00 = (z0 * HH + y0) * WW;
    int o01 = (z0 * HH + y1) * WW;
    int o10 = (z1 * HH + y0) * WW;
    int o11 = (z1 * HH + y1) * WW;

    float omx = 1.0f - wx, omy = 1.0f - wy, omz = 1.0f - wz;

    #pragma unroll
    for (int c = 0; c < 3; ++c) {
        const float* p = src + c * NVOX;
        float c000 = p[o00 + x0], c001 = p[o00 + x1];
        float c010 = p[o01 + x0], c011 = p[o01 + x1];
        float c100 = p[o10 + x0], c101 = p[o10 + x1];
        float c110 = p[o11 + x0], c111 = p[o11 + x1];
        float top = (c000 * omx + c001 * wx) * omy + (c010 * omx + c011 * wx) * wy;
        float bot = (c100 * omx + c101 * wx) * omy + (c110 * omx + c111 * wx) * wy;
        float val = top * omz + bot * wz;
        float fcur = (c == 0) ? fx : ((c == 1) ? fy : fz);
        dst[c * NVOX + idx] = fcur + val;
    }
}

// ---------------- launch ----------------
extern "C" void kernel_launch(void* const* d_in, const int* in_sizes, int n_in,
                              void* d_out, int out_size, void* d_ws, size_t ws_size,
                              hipStream_t stream) {
    const float* vel  = (const float*)d_in[0];   // [1,3,128,128,128]
    const float* grid = (const float*)d_in[1];   // [1,128,128,128,3]
    float* out = (float*)d_out;

    const size_t aos_bytes = (size_t)NVOX * 16;  // 32 MiB per buffer
    const size_t tbl_bytes = 4096;               // 3*128 floats, padded

    if (ws_size >= 2 * aos_bytes + tbl_bytes) {
        // Fast path: fused init+step1 (LDS tile) + blocked ping-pong.
        float* tbl = (float*)d_ws;
        float4* A = (float4*)((char*)d_ws + tbl_bytes);
        float4* B = A + NVOX;

        // Step 1 (with init fused): 4096 tiles of 8^3, 512 threads each.
        fused_step1_kernel<<<4096, 512, 0, stream>>>(vel, grid, A, tbl);

        // Steps 2..6 blocked ping-pong: A->B->A->B->A->B
        const float4* cur = A;
        for (int it = 0; it < 5; ++it) {
            float4* nxt = (it & 1) ? A : B;
            warp_step_blk_kernel<false><<<(NVOX + 255) / 256, 256, 0, stream>>>(
                cur, tbl, nxt, nullptr);
            cur = nxt;
        }
        // Step 7 writes planar f32 straight to d_out.
        warp_step_blk_kernel<true><<<(NVOX + 255) / 256, 256, 0, stream>>>(
            cur, tbl, nullptr, out);
    } else if (ws_size >= 2 * aos_bytes) {
        // Linear AoS path with grid reads (R2).
        float4* A = (float4*)d_ws;
        float4* B = A + NVOX;
        init_flow_aos_kernel<<<(NVOX + 255) / 256, 256, 0, stream>>>(vel, A);
        const float4* cur = A;
        for (int it = 0; it < 6; ++it) {
            float4* nxt = (it & 1) ? A : B;
            warp_step_aos_kernel<false><<<(NVOX + 255) / 256, 256, 0, stream>>>(
                cur, grid, nxt, nullptr);
            cur = nxt;
        }
        warp_step_aos_kernel<true><<<(NVOX + 255) / 256, 256, 0, stream>>>(
            cur, grid, nullptr, out);
    } else {
        // Planar fallback (24 MiB ws).
        float* ws = (float*)d_ws;
        init_flow_kernel<<<(NELEM + 255) / 256, 256, 0, stream>>>(vel, ws);
        const float* cur = ws;
        for (int it = 0; it < 7; ++it) {
            float* nxt = (it & 1) ? ws : out;
            warp_step_kernel<<<(NVOX + 255) / 256, 256, 0, stream>>>(cur, grid, nxt);
            cur = nxt;
        }
    }
}

// Round 8
// 196.223 us; speedup vs baseline: 1.0201x; 1.0201x over previous
//
#include <hip/hip_runtime.h>

// DiffeomorphicTransform: scaling-and-squaring integration of a velocity field.
//   flow = velocity / 2^7
//   repeat 7x: flow = flow + trilinear_sample(flow, sample_grid + flow_perm)
// Volume: B=1, C=3, D=H=W=128, f32.
//
// R2: AoS float4 flow -> 8 dwordx4 gathers/voxel. 92->50us/step.
// R3: separable grid -> 3x128 LDS axis tables (gather-transaction bound).
// R4: 2x2x2 supervoxel layout (one 128B line per 2x2x2 block). 278->201us.
// R5: FAILED global-gather fusion of init+step1 (scalar gather count rules).
// R6: blocked-order init (coalesced writes). 201->196us.  <-- this version
// R7: FAILED LDS-tile fusion of init+step1 (8x halo overfetch per-XCD,
//     grid re-read, bank conflicts -> 43us vs 32us split). Reverted.
// Conclusion: late steps sit at the L1/TCP line-transaction floor
// (~8 unique lines per wave-gather); HBM 3%, VALU 11% -> structural.

#define DD 128
#define HH 128
#define WW 128
#define NVOX (DD * HH * WW)          // 2,097,152
#define NELEM (3 * NVOX)             // 6,291,456
#define SCALE 63.5f                  // 0.5*(dim-1), same for x/y/z
#define INV128 (1.0f / 128.0f)

// float4-index of voxel (x,y,z) in the 2x2x2-blocked volume.
__device__ __forceinline__ int blk_addr4(int xc, int yc, int zc) {
    return ((zc >> 1) << 15) + ((yc >> 1) << 9) + ((xc >> 1) << 3)
         + ((zc & 1) << 2) + ((yc & 1) << 1) + (xc & 1);
}

// ---------------- init: flow0 = vel/128, blocked-order (coalesced writes) ---
// Also extracts the 3x128 axis tables (block 0 only; bit-identical values:
// grid [D][H][W][3] is a broadcast meshgrid).
__global__ __launch_bounds__(256) void init_blk_kernel(
    const float* __restrict__ vel,     // [3][D][H][W] planar
    const float* __restrict__ grid,    // [D][H][W][3]
    float4* __restrict__ flow,         // blocked AoS out
    float* __restrict__ tbl) {         // [384] axis tables out
    if (blockIdx.x == 0) {
        int i = threadIdx.x;
        if (i < 128) {
            tbl[i]       = grid[3 * i + 0];                  // t_x[w]
            tbl[128 + i] = grid[(i * WW) * 3 + 1];           // t_y[h]
            tbl[256 + i] = grid[(i * HH * WW) * 3 + 2];      // t_z[d]
        }
    }

    int gid = blockIdx.x * blockDim.x + threadIdx.x;   // blocked index
    if (gid >= NVOX) return;

    int phase = gid & 7;
    int sv = gid >> 3;
    int x = ((sv & 63) << 1) | (phase & 1);
    int y = (((sv >> 6) & 63) << 1) | ((phase >> 1) & 1);
    int z = ((sv >> 12) << 1) | ((phase >> 2) & 1);
    int lin = (z * HH + y) * WW + x;

    float4 f;
    f.x = vel[lin] * INV128;
    f.y = vel[NVOX + lin] * INV128;
    f.z = vel[2 * NVOX + lin] * INV128;
    f.w = 0.0f;
    flow[gid] = f;                     // coalesced blocked write
}

// ---------------- warp step, blocked layout ----------------
template <bool PLANAR_OUT>
__global__ __launch_bounds__(256) void warp_step_blk_kernel(
    const float4* __restrict__ src,    // blocked AoS flow
    const float* __restrict__ tbl,     // [384] axis tables
    float4* __restrict__ dst4,         // blocked AoS out (if !PLANAR_OUT)
    float* __restrict__ dstp) {        // planar out (if PLANAR_OUT)
    __shared__ float s_tx[128], s_ty[128], s_tz[128];
    int tid = threadIdx.x;
    if (tid < 128) {
        s_tx[tid] = tbl[tid];
        s_tz[tid] = tbl[256 + tid];
    } else {
        s_ty[tid - 128] = tbl[tid];
    }
    __syncthreads();

    int gid = blockIdx.x * blockDim.x + threadIdx.x;
    if (gid >= NVOX) return;

    int phase = gid & 7;
    int sv = gid >> 3;
    int x = ((sv & 63) << 1) | (phase & 1);
    int y = (((sv >> 6) & 63) << 1) | ((phase >> 1) & 1);
    int z = ((sv >> 12) << 1) | ((phase >> 2) & 1);

    float4 f = src[gid];               // coalesced self-read

    float xs = (s_tx[x] + f.x + 1.0f) * SCALE;
    float ys = (s_ty[y] + f.y + 1.0f) * SCALE;
    float zs = (s_tz[z] + f.z + 1.0f) * SCALE;

    float x0f = floorf(xs), y0f = floorf(ys), z0f = floorf(zs);
    float wx = xs - x0f, wy = ys - y0f, wz = zs - z0f;
    float omx = 1.0f - wx, omy = 1.0f - wy, omz = 1.0f - wz;

    int x0 = min(max((int)x0f, 0), WW - 1);
    int x1 = min(max((int)x0f + 1, 0), WW - 1);
    int y0 = min(max((int)y0f, 0), HH - 1);
    int y1 = min(max((int)y0f + 1, 0), HH - 1);
    int z0 = min(max((int)z0f, 0), DD - 1);
    int z1 = min(max((int)z0f + 1, 0), DD - 1);

    float4 c000 = src[blk_addr4(x0, y0, z0)];
    float4 c001 = src[blk_addr4(x1, y0, z0)];
    float4 c010 = src[blk_addr4(x0, y1, z0)];
    float4 c011 = src[blk_addr4(x1, y1, z0)];
    float4 c100 = src[blk_addr4(x0, y0, z1)];
    float4 c101 = src[blk_addr4(x1, y0, z1)];
    float4 c110 = src[blk_addr4(x0, y1, z1)];
    float4 c111 = src[blk_addr4(x1, y1, z1)];

    float vx, vy, vzv;
    {
        float t, b;
        t = (c000.x * omx + c001.x * wx) * omy + (c010.x * omx + c011.x * wx) * wy;
        b = (c100.x * omx + c101.x * wx) * omy + (c110.x * omx + c111.x * wx) * wy;
        vx = t * omz + b * wz;
        t = (c000.y * omx + c001.y * wx) * omy + (c010.y * omx + c011.y * wx) * wy;
        b = (c100.y * omx + c101.y * wx) * omy + (c110.y * omx + c111.y * wx) * wy;
        vy = t * omz + b * wz;
        t = (c000.z * omx + c001.z * wx) * omy + (c010.z * omx + c011.z * wx) * wy;
        b = (c100.z * omx + c101.z * wx) * omy + (c110.z * omx + c111.z * wx) * wy;
        vzv = t * omz + b * wz;
    }

    if (PLANAR_OUT) {
        int lin = (z * HH + y) * WW + x;
        dstp[lin] = f.x + vx;
        dstp[NVOX + lin] = f.y + vy;
        dstp[2 * NVOX + lin] = f.z + vzv;
    } else {
        float4 o;
        o.x = f.x + vx;
        o.y = f.y + vy;
        o.z = f.z + vzv;
        o.w = 0.0f;
        dst4[gid] = o;                 // coalesced
    }
}

// ---------------- linear-AoS path (fallback, mid ws) ----------------
__global__ __launch_bounds__(256) void init_flow_aos_kernel(
    const float* __restrict__ vel, float4* __restrict__ flow) {
    int i = blockIdx.x * blockDim.x + threadIdx.x;
    if (i >= NVOX) return;
    float4 f;
    f.x = vel[i] * INV128;
    f.y = vel[NVOX + i] * INV128;
    f.z = vel[2 * NVOX + i] * INV128;
    f.w = 0.0f;
    flow[i] = f;
}

template <bool PLANAR_OUT>
__global__ __launch_bounds__(256) void warp_step_aos_kernel(
    const float4* __restrict__ src, const float* __restrict__ grid,
    float4* __restrict__ dst4, float* __restrict__ dstp) {
    int idx = blockIdx.x * blockDim.x + threadIdx.x;
    if (idx >= NVOX) return;

    float4 f = src[idx];
    float gx = grid[3 * idx + 0];
    float gy = grid[3 * idx + 1];
    float gz = grid[3 * idx + 2];

    float x = (gx + f.x + 1.0f) * SCALE;
    float y = (gy + f.y + 1.0f) * SCALE;
    float z = (gz + f.z + 1.0f) * SCALE;

    float x0f = floorf(x), y0f = floorf(y), z0f = floorf(z);
    float wx = x - x0f, wy = y - y0f, wz = z - z0f;
    float omx = 1.0f - wx, omy = 1.0f - wy, omz = 1.0f - wz;

    int x0 = min(max((int)x0f, 0), WW - 1);
    int x1 = min(max((int)x0f + 1, 0), WW - 1);
    int y0 = min(max((int)y0f, 0), HH - 1);
    int y1 = min(max((int)y0f + 1, 0), HH - 1);
    int z0 = min(max((int)z0f, 0), DD - 1);
    int z1 = min(max((int)z0f + 1, 0), DD - 1);

    const float4* r00 = src + (z0 * HH + y0) * WW;
    const float4* r01 = src + (z0 * HH + y1) * WW;
    const float4* r10 = src + (z1 * HH + y0) * WW;
    const float4* r11 = src + (z1 * HH + y1) * WW;

    float4 c000 = r00[x0], c001 = r00[x1];
    float4 c010 = r01[x0], c011 = r01[x1];
    float4 c100 = r10[x0], c101 = r10[x1];
    float4 c110 = r11[x0], c111 = r11[x1];

    float vx, vy, vzv;
    {
        float t, b;
        t = (c000.x * omx + c001.x * wx) * omy + (c010.x * omx + c011.x * wx) * wy;
        b = (c100.x * omx + c101.x * wx) * omy + (c110.x * omx + c111.x * wx) * wy;
        vx = t * omz + b * wz;
        t = (c000.y * omx + c001.y * wx) * omy + (c010.y * omx + c011.y * wx) * wy;
        b = (c100.y * omx + c101.y * wx) * omy + (c110.y * omx + c111.y * wx) * wy;
        vy = t * omz + b * wz;
        t = (c000.z * omx + c001.z * wx) * omy + (c010.z * omx + c011.z * wx) * wy;
        b = (c100.z * omx + c101.z * wx) * omy + (c110.z * omx + c111.z * wx) * wy;
        vzv = t * omz + b * wz;
    }

    if (PLANAR_OUT) {
        dstp[idx] = f.x + vx;
        dstp[NVOX + idx] = f.y + vy;
        dstp[2 * NVOX + idx] = f.z + vzv;
    } else {
        float4 o;
        o.x = f.x + vx; o.y = f.y + vy; o.z = f.z + vzv; o.w = 0.0f;
        dst4[idx] = o;
    }
}

// ---------------- planar fallback (tiny ws) ----------------
__global__ __launch_bounds__(256) void init_flow_kernel(
    const float* __restrict__ vel, float* __restrict__ flow) {
    int i = blockIdx.x * blockDim.x + threadIdx.x;
    if (i < NELEM) flow[i] = vel[i] * INV128;
}

__global__ __launch_bounds__(256) void warp_step_kernel(
    const float* __restrict__ src, const float* __restrict__ grid,
    float* __restrict__ dst) {
    int idx = blockIdx.x * blockDim.x + threadIdx.x;
    if (idx >= NVOX) return;

    float fx = src[idx];
    float fy = src[NVOX + idx];
    float fz = src[2 * NVOX + idx];
    float gx = grid[idx * 3 + 0];
    float gy = grid[idx * 3 + 1];
    float gz = grid[idx * 3 + 2];

    float x = (gx + fx + 1.0f) * SCALE;
    float y = (gy + fy + 1.0f) * SCALE;
    float z = (gz + fz + 1.0f) * SCALE;

    float x0f = floorf(x), y0f = floorf(y), z0f = floorf(z);
    float wx = x - x0f, wy = y - y0f, wz = z - z0f;

    int x0 = min(max((int)x0f, 0), WW - 1);
    int x1 = min(max((int)x0f + 1, 0), WW - 1);
    int y0 = min(max((int)y0f, 0), HH - 1);
    int y1 = min(max((int)y0f + 1, 0), HH - 1);
    int z0 = min(max((int)z0f, 0), DD - 1);
    int z1 = min(max((int)z0f + 1, 0), DD - 1);

    int o00 = (z0 * HH + y0) * WW;
    int o01 = (z0 * HH + y1) * WW;
    int o10 = (z1 * HH + y0) * WW;
    int o11 = (z1 * HH + y1) * WW;

    float omx = 1.0f - wx, omy = 1.0f - wy, omz = 1.0f - wz;

    #pragma unroll
    for (int c = 0; c < 3; ++c) {
        const float* p = src + c * NVOX;
        float c000 = p[o00 + x0], c001 = p[o00 + x1];
        float c010 = p[o01 + x0], c011 = p[o01 + x1];
        float c100 = p[o10 + x0], c101 = p[o10 + x1];
        float c110 = p[o11 + x0], c111 = p[o11 + x1];
        float top = (c000 * omx + c001 * wx) * omy + (c010 * omx + c011 * wx) * wy;
        float bot = (c100 * omx + c101 * wx) * omy + (c110 * omx + c111 * wx) * wy;
        float val = top * omz + bot * wz;
        float fcur = (c == 0) ? fx : ((c == 1) ? fy : fz);
        dst[c * NVOX + idx] = fcur + val;
    }
}

// ---------------- launch ----------------
extern "C" void kernel_launch(void* const* d_in, const int* in_sizes, int n_in,
                              void* d_out, int out_size, void* d_ws, size_t ws_size,
                              hipStream_t stream) {
    const float* vel  = (const float*)d_in[0];   // [1,3,128,128,128]
    const float* grid = (const float*)d_in[1];   // [1,128,128,128,3]
    float* out = (float*)d_out;

    const size_t aos_bytes = (size_t)NVOX * 16;  // 32 MiB per buffer
    const size_t tbl_bytes = 4096;               // 3*128 floats, padded

    if (ws_size >= 2 * aos_bytes + tbl_bytes) {
        // Fast path: blocked-order init (tables folded in) + blocked ping-pong.
        float* tbl = (float*)d_ws;
        float4* A = (float4*)((char*)d_ws + tbl_bytes);
        float4* B = A + NVOX;

        init_blk_kernel<<<(NVOX + 255) / 256, 256, 0, stream>>>(vel, grid, A, tbl);

        // Steps 1..6 blocked ping-pong: A->B->A->B->A->B->A
        const float4* cur = A;
        for (int it = 0; it < 6; ++it) {
            float4* nxt = (it & 1) ? A : B;
            warp_step_blk_kernel<false><<<(NVOX + 255) / 256, 256, 0, stream>>>(
                cur, tbl, nxt, nullptr);
            cur = nxt;
        }
        // Step 7 writes planar f32 straight to d_out.
        warp_step_blk_kernel<true><<<(NVOX + 255) / 256, 256, 0, stream>>>(
            cur, tbl, nullptr, out);
    } else if (ws_size >= 2 * aos_bytes) {
        // Linear AoS path with grid reads (R2).
        float4* A = (float4*)d_ws;
        float4* B = A + NVOX;
        init_flow_aos_kernel<<<(NVOX + 255) / 256, 256, 0, stream>>>(vel, A);
        const float4* cur = A;
        for (int it = 0; it < 6; ++it) {
            float4* nxt = (it & 1) ? A : B;
            warp_step_aos_kernel<false><<<(NVOX + 255) / 256, 256, 0, stream>>>(
                cur, grid, nxt, nullptr);
            cur = nxt;
        }
        warp_step_aos_kernel<true><<<(NVOX + 255) / 256, 256, 0, stream>>>(
            cur, grid, nullptr, out);
    } else {
        // Planar fallback (24 MiB ws).
        float* ws = (float*)d_ws;
        init_flow_kernel<<<(NELEM + 255) / 256, 256, 0, stream>>>(vel, ws);
        const float* cur = ws;
        for (int it = 0; it < 7; ++it) {
            float* nxt = (it & 1) ? ws : out;
            warp_step_kernel<<<(NVOX + 255) / 256, 256, 0, stream>>>(cur, grid, nxt);
            cur = nxt;
        }
    }
}